// Round 8
// baseline (487.477 us; speedup 1.0000x reference)
//
#include <hip/hip_runtime.h>

// GCN r8: edge-balanced gather. Tile's CSR edge range split into 64 equal
// chunks (one per lane-group); register run-accumulation per dst + LDS fp32
// atomic flush into 64x97 accumulator (overlaid with split-bf16 A-tile LDS).
// Removes the max-degree straggler tax of the per-node gather.

constexpr int NN   = 50000;
constexpr int NE   = 800000;
constexpr int KIN  = 512;
constexpr int HIDD = 96;
constexpr int ODIM = 64;
constexpr int NBLK = (NN + 255) / 256;   // 196 scan blocks

typedef short bf16x8 __attribute__((ext_vector_type(8)));
typedef float f32x4  __attribute__((ext_vector_type(4)));
typedef _Float16 h4  __attribute__((ext_vector_type(4)));

__device__ inline short f2bf(float f) {               // RTN-even fp32 -> bf16 bits
    union { float f; unsigned u; } v; v.f = f;
    unsigned r = v.u + 0x7FFFu + ((v.u >> 16) & 1u);
    return (short)(r >> 16);
}
__device__ inline short f2bf_trunc(float f) {         // truncate (for lo residual)
    union { float f; unsigned u; } v; v.f = f;
    return (short)(v.u >> 16);
}
__device__ inline float bf2f(short h) {
    union { unsigned u; float f; } v; v.u = ((unsigned)(unsigned short)h) << 16;
    return v.f;
}

// ---------------- CSR build ----------------
__global__ void zero_int_kernel(int* __restrict__ p, int n) {
    int i = blockIdx.x * blockDim.x + threadIdx.x;
    if (i < n) p[i] = 0;
}

__global__ void hist_kernel(const int* __restrict__ dst, int* __restrict__ deg) {
    int e = blockIdx.x * blockDim.x + threadIdx.x;
    if (e < NE) atomicAdd(&deg[dst[e]], 1);
}

__global__ void scan1_kernel(const int* __restrict__ deg, int* __restrict__ excl,
                             int* __restrict__ partials) {
    __shared__ int tmp[256];
    const int tid = threadIdx.x;
    const int i = blockIdx.x * 256 + tid;
    const int v = (i < NN) ? deg[i] : 0;
    tmp[tid] = v;
    __syncthreads();
#pragma unroll
    for (int off = 1; off < 256; off <<= 1) {
        int t = (tid >= off) ? tmp[tid - off] : 0;
        __syncthreads();
        tmp[tid] += t;
        __syncthreads();
    }
    if (i < NN) excl[i] = tmp[tid] - v;
    if (tid == 255) partials[blockIdx.x] = tmp[tid];
}

__global__ void scan3_kernel(const int* __restrict__ excl, const int* __restrict__ partials,
                             const int* __restrict__ deg, int* __restrict__ rowstart,
                             float* __restrict__ dinv, int* __restrict__ cursor) {
    __shared__ int tmp[256];
    const int tid = threadIdx.x;
    tmp[tid] = (tid < (int)blockIdx.x) ? partials[tid] : 0;   // NBLK=196 <= 256
    __syncthreads();
#pragma unroll
    for (int off = 128; off > 0; off >>= 1) {
        if (tid < off) tmp[tid] += tmp[tid + off];
        __syncthreads();
    }
    const int boff = tmp[0];
    const int i = blockIdx.x * 256 + tid;
    if (i < NN) {
        rowstart[i] = excl[i] + boff;
        dinv[i] = 1.0f / sqrtf((float)deg[i] + 1.0f);
        cursor[i] = 0;
    }
    if (blockIdx.x == 0 && tid == 0) rowstart[NN] = NE;   // sentinel for tile edge ranges
}

// csr_src packs src (bits 0..19) | dst-local (bits 20..25)
__global__ void scatter_kernel(const int* __restrict__ src, const int* __restrict__ dst,
                               const int* __restrict__ rowstart, int* __restrict__ cursor,
                               int* __restrict__ csr_src) {
    int e = blockIdx.x * blockDim.x + threadIdx.x;
    if (e < NE) {
        const int d = dst[e];
        const int pos = rowstart[d] + atomicAdd(&cursor[d], 1);
        csr_src[pos] = src[e] | ((d & 63) << 20);
    }
}

// ---------------- fused W hi/lo pack (MFMA B-frag order) ----------------
__global__ void pack_all(const float* __restrict__ W0, const float* __restrict__ W1,
                         const float* __restrict__ W2, const float* __restrict__ FC,
                         short* __restrict__ w0hi, short* __restrict__ w0lo,
                         short* __restrict__ w1hi, short* __restrict__ w1lo,
                         short* __restrict__ w2hi, short* __restrict__ w2lo,
                         short* __restrict__ fchi, short* __restrict__ fclo) {
    const int idx = blockIdx.x * 256 + threadIdx.x;
    const float* W; short *hi, *lo; int M, li;
    if      (idx < 49152) { W = W0; hi = w0hi; lo = w0lo; M = 96; li = idx; }
    else if (idx < 58368) { W = W1; hi = w1hi; lo = w1lo; M = 96; li = idx - 49152; }
    else if (idx < 67584) { W = W2; hi = w2hi; lo = w2lo; M = 96; li = idx - 58368; }
    else if (idx < 73728) { W = FC; hi = fchi; lo = fclo; M = 64; li = idx - 67584; }
    else return;
    const int CT = M >> 4;
    const int j = li & 7;
    const int lane = (li >> 3) & 63;
    const int t = li >> 9;             // kc*CT + ct
    const int ct = t % CT;
    const int kc = t / CT;
    const int k = kc * 32 + (lane >> 4) * 8 + j;
    const int n = ct * 16 + (lane & 15);
    const float w = W[k * M + n];
    const short h = f2bf(w);
    hi[li] = h;
    lo[li] = f2bf_trunc(w - bf2f(h));
}

// ---------------- layer-0 GEMM: fp32 A, split-bf16, split-K x2, LDS-staged W ----
template <int K>   // 512
__launch_bounds__(512, 6)
__global__ void mfma_gemm_f(const float* __restrict__ A, const short* __restrict__ Whi,
                            const short* __restrict__ Wlo, const float* __restrict__ dinv,
                            _Float16* __restrict__ C, int N) {
    constexpr int CT = 6;
    constexpr int KCH = K / 64;        // kc per half = 8
    constexpr int PH  = KCH / 2;       // 4 phases, 2 kc per half per phase
    __shared__ short sHi[4 * 3072];    // 24 KB
    __shared__ short sLo[4 * 3072];    // 24 KB

    const int tid = threadIdx.x;
    const int lane = tid & 63;
    const int wave = tid >> 6;
    const int rw = wave & 3;
    const int kh = wave >> 2;
    const int q = lane >> 4;
    const int m = lane & 15;
    const int row = blockIdx.x * 64 + rw * 16 + m;
    const int arow = (row < N) ? row : (N - 1);

    f32x4 acc[CT];
#pragma unroll
    for (int c = 0; c < CT; ++c) acc[c] = f32x4{0.f, 0.f, 0.f, 0.f};

    const float* ap = A + (size_t)arow * K + kh * (K / 2) + q * 8;
    float4 a0 = *(const float4*)(ap);
    float4 a1 = *(const float4*)(ap + 4);

#pragma unroll
    for (int p = 0; p < PH; ++p) {
#pragma unroll
        for (int i = 0; i < 3; ++i) {
            const int ci = i * 512 + tid;            // 0..1535
            const int slot = ci / 384;               // 384 f4 per group
            const int within = ci - slot * 384;
            const int kcg = (slot >> 1) * KCH + p * 2 + (slot & 1);
            const int so = kcg * 3072 + within * 8;
            const int doff = ci * 8;
            *(float4*)(sHi + doff) = *(const float4*)(Whi + so);
            *(float4*)(sLo + doff) = *(const float4*)(Wlo + so);
        }
        __syncthreads();

#pragma unroll
        for (int kc = 0; kc < 2; ++kc) {
            const float af[8] = {a0.x, a0.y, a0.z, a0.w, a1.x, a1.y, a1.z, a1.w};
            bf16x8 ahi, alo;
#pragma unroll
            for (int j = 0; j < 8; ++j) {
                const short h = f2bf(af[j]);
                ahi[j] = h;
                alo[j] = f2bf_trunc(af[j] - bf2f(h));
            }
            if (p * 2 + kc + 1 < KCH) {
                ap += 32;
                a0 = *(const float4*)(ap);
                a1 = *(const float4*)(ap + 4);
            }
            const int slot = kh * 2 + kc;
            const short* hbase = sHi + slot * 3072 + lane * 8;
            const short* lbase = sLo + slot * 3072 + lane * 8;
#pragma unroll
            for (int c = 0; c < CT; ++c) {
                const bf16x8 wh = *(const bf16x8*)(hbase + c * 512);
                const bf16x8 wl = *(const bf16x8*)(lbase + c * 512);
                acc[c] = __builtin_amdgcn_mfma_f32_16x16x32_bf16(ahi, wh, acc[c], 0, 0, 0);
                acc[c] = __builtin_amdgcn_mfma_f32_16x16x32_bf16(alo, wh, acc[c], 0, 0, 0);
                acc[c] = __builtin_amdgcn_mfma_f32_16x16x32_bf16(ahi, wl, acc[c], 0, 0, 0);
            }
        }
        __syncthreads();
    }

    // split-K combine via LDS (reuse staging buffers)
    float* sAcc = (float*)sHi;
    if (kh == 1) {
#pragma unroll
        for (int c = 0; c < CT; ++c)
            *(f32x4*)(sAcc + ((rw * 64 + lane) * CT + c) * 4) = acc[c];
    }
    __syncthreads();
    if (kh == 0) {
#pragma unroll
        for (int c = 0; c < CT; ++c) {
            const f32x4 o = *(const f32x4*)(sAcc + ((rw * 64 + lane) * CT + c) * 4);
            acc[c][0] += o[0]; acc[c][1] += o[1]; acc[c][2] += o[2]; acc[c][3] += o[3];
        }
        const int rbase = blockIdx.x * 64 + rw * 16 + q * 4;
#pragma unroll
        for (int r = 0; r < 4; ++r) {
            const int orow = rbase + r;
            if (orow < N) {
                const float s = dinv[orow];
#pragma unroll
                for (int c = 0; c < CT; ++c)
                    C[(size_t)orow * 96 + c * 16 + m] = (_Float16)(acc[c][r] * s);
            }
        }
    }
}

// ---------------- fused gather + GEMM (edge-balanced gather) ----------------
constexpr int APAD = 104;   // LDS A-tile row stride in shorts
constexpr int ACCS = 97;    // LDS fp32 accumulator row stride (bank-decorrelated)
template <int M, bool FC>
__launch_bounds__(512, 6)
__global__ void fused_gg(const int* __restrict__ rowstart, const float* __restrict__ dinv,
                         const int* __restrict__ csr_src, const h4* __restrict__ hs,
                         const float* __restrict__ gb,
                         const short* __restrict__ Whi, const short* __restrict__ Wlo,
                         const float* __restrict__ bias2,
                         _Float16* __restrict__ Ch, float* __restrict__ Cf, int N) {
    constexpr int CT = M / 16;     // 6 or 4
    constexpr int CTH = CT / 2;    // 3 or 2
    __shared__ short SMEM[2 * 64 * APAD];        // 26624 B
    float* accf = (float*)SMEM;                  // 64*97*4 = 24832 B (overlaid)
    short* sAhi = SMEM;
    short* sAlo = SMEM + 64 * APAD;

    const int tid = threadIdx.x;
    const int nb = blockIdx.x * 64;

    // zero fp32 accumulators
    for (int i = tid; i < 64 * ACCS; i += 512) accf[i] = 0.0f;
    __syncthreads();

    // ---- edge-balanced gather: 64 groups x 8 feat-lanes ----
    {
        const int e0 = rowstart[nb];
        const int top = (nb + 64 < N) ? nb + 64 : N;
        const int T = rowstart[top] - e0;
        const int g = tid >> 3;
        const int f8 = tid & 7;
        const int per = (T + 63) >> 6;
        int j = g * per;
        const int jend = (j + per < T) ? (j + per) : T;

        float racc[12];
#pragma unroll
        for (int i = 0; i < 12; ++i) racc[i] = 0.f;
        int curloc = -1;
        int v = (j < jend) ? csr_src[e0 + j] : 0;
        while (j < jend) {
            const int vn = (j + 1 < jend) ? csr_src[e0 + j + 1] : 0;
            const int s = v & 0xFFFFF;
            const int loc = v >> 20;
            if (loc != curloc) {
                if (curloc >= 0) {
#pragma unroll
                    for (int i = 0; i < 12; ++i)
                        atomicAdd(&accf[curloc * ACCS + f8 * 12 + i], racc[i]);
                }
#pragma unroll
                for (int i = 0; i < 12; ++i) racc[i] = 0.f;
                curloc = loc;
            }
            const h4* __restrict__ p = hs + (size_t)s * 24 + f8 * 3;
            const h4 p0 = p[0], p1 = p[1], p2 = p[2];
#pragma unroll
            for (int e = 0; e < 4; ++e) {
                racc[e] += (float)p0[e]; racc[4 + e] += (float)p1[e]; racc[8 + e] += (float)p2[e];
            }
            v = vn; ++j;
        }
        if (curloc >= 0) {
#pragma unroll
            for (int i = 0; i < 12; ++i)
                atomicAdd(&accf[curloc * ACCS + f8 * 12 + i], racc[i]);
        }
    }
    __syncthreads();

    // ---- finalize into registers: self-loop + dinv + bias + relu + split-bf16 ----
    const int nl = tid >> 3;
    const int fc8 = tid & 7;
    const int node = nb + nl;
    short hi[12], lo[12];
    if (node < N) {
        const h4* __restrict__ hp = hs + (size_t)node * 24 + fc8 * 3;
        const h4 s0 = hp[0], s1 = hp[1], s2 = hp[2];
        const float di = dinv[node];
        float a[12];
#pragma unroll
        for (int i = 0; i < 12; ++i) a[i] = accf[nl * ACCS + fc8 * 12 + i];
#pragma unroll
        for (int e = 0; e < 4; ++e) {
            a[e] += (float)s0[e]; a[4 + e] += (float)s1[e]; a[8 + e] += (float)s2[e];
        }
#pragma unroll
        for (int i = 0; i < 12; ++i) {
            const float o = fmaxf(fmaf(di, a[i], gb[fc8 * 12 + i]), 0.0f);
            hi[i] = f2bf(o);
            lo[i] = f2bf_trunc(o - bf2f(hi[i]));
        }
    } else {
#pragma unroll
        for (int i = 0; i < 12; ++i) { hi[i] = 0; lo[i] = 0; }
    }
    __syncthreads();   // accf reads complete before overlay store

    short* dh = sAhi + nl * APAD + fc8 * 12;
    short* dl = sAlo + nl * APAD + fc8 * 12;
#pragma unroll
    for (int t = 0; t < 3; ++t) {
        *(short4*)(dh + t * 4) = make_short4(hi[4 * t], hi[4 * t + 1], hi[4 * t + 2], hi[4 * t + 3]);
        *(short4*)(dl + t * 4) = make_short4(lo[4 * t], lo[4 * t + 1], lo[4 * t + 2], lo[4 * t + 3]);
    }
    __syncthreads();

    // ---- GEMM phase: 8 waves = 4 row groups x 2 column halves ----
    const int lane = tid & 63;
    const int wave = tid >> 6;
    const int rw = wave & 3;
    const int c0 = (wave >> 2) * CTH;
    const int q = lane >> 4;
    const int m = lane & 15;

    bf16x8 Ah[3], Al[3];
#pragma unroll
    for (int kc = 0; kc < 3; ++kc) {
        const int off = (rw * 16 + m) * APAD + kc * 32 + q * 8;
        Ah[kc] = *(const bf16x8*)(sAhi + off);
        Al[kc] = *(const bf16x8*)(sAlo + off);
    }

    f32x4 gacc[CTH];
#pragma unroll
    for (int c = 0; c < CTH; ++c) gacc[c] = f32x4{0.f, 0.f, 0.f, 0.f};

#pragma unroll
    for (int kc = 0; kc < 3; ++kc) {
#pragma unroll
        for (int c = 0; c < CTH; ++c) {
            const int fo = ((kc * CT + c0 + c) * 64 + lane) * 8;
            const bf16x8 wh = *(const bf16x8*)(Whi + fo);
            const bf16x8 wl = *(const bf16x8*)(Wlo + fo);
            gacc[c] = __builtin_amdgcn_mfma_f32_16x16x32_bf16(Ah[kc], wh, gacc[c], 0, 0, 0);
            gacc[c] = __builtin_amdgcn_mfma_f32_16x16x32_bf16(Al[kc], wh, gacc[c], 0, 0, 0);
            gacc[c] = __builtin_amdgcn_mfma_f32_16x16x32_bf16(Ah[kc], wl, gacc[c], 0, 0, 0);
        }
    }

    const int rbase = nb + rw * 16 + q * 4;
#pragma unroll
    for (int r = 0; r < 4; ++r) {
        const int orow = rbase + r;
        if (orow < N) {
            if (FC) {
#pragma unroll
                for (int c = 0; c < CTH; ++c)
                    Cf[(size_t)orow * M + (c0 + c) * 16 + m] = gacc[c][r] + bias2[(c0 + c) * 16 + m];
            } else {
                const float s = dinv[orow];
#pragma unroll
                for (int c = 0; c < CTH; ++c)
                    Ch[(size_t)orow * M + (c0 + c) * 16 + m] = (_Float16)(gacc[c][r] * s);
            }
        }
    }
}

extern "C" void kernel_launch(void* const* d_in, const int* in_sizes, int n_in,
                              void* d_out, int out_size, void* d_ws, size_t ws_size,
                              hipStream_t stream) {
    const float* x   = (const float*)d_in[0];
    const int*   ei  = (const int*)d_in[1];
    const float* W0  = (const float*)d_in[2];
    const float* b0  = (const float*)d_in[3];
    const float* W1  = (const float*)d_in[4];
    const float* b1  = (const float*)d_in[5];
    const float* W2  = (const float*)d_in[6];
    const float* b2  = (const float*)d_in[7];
    const float* fcW = (const float*)d_in[8];
    const float* fcb = (const float*)d_in[9];
    float* out = (float*)d_out;

    const int* src = ei;
    const int* dst = ei + NE;

    float* ws = (float*)d_ws;
    float* dinv     = ws;                       // [50000]
    int*   deg      = (int*)(ws + 50176);
    int*   excl     = (int*)(ws + 100352);
    int*   cursor   = (int*)(ws + 150528);
    int*   rowstart = (int*)(ws + 200704);      // [50001] (sentinel)
    int*   partials = (int*)(ws + 250880);      // [256]
    int*   csr_src  = (int*)(ws + 251136);      // [800000] packed src|loc<<20
    short* w0hi = (short*)(ws + 1051392);       // [49152] shorts
    short* w0lo = (short*)(ws + 1075968);
    short* w1hi = (short*)(ws + 1100544);       // [9216] shorts
    short* w1lo = (short*)(ws + 1105152);
    short* w2hi = (short*)(ws + 1109760);
    short* w2lo = (short*)(ws + 1114368);
    short* fchi = (short*)(ws + 1118976);       // [6144] shorts
    short* fclo = (short*)(ws + 1122048);
    _Float16* hsA = (_Float16*)(ws + 1125120);  // [4.8M halves]
    _Float16* hsB = (_Float16*)(ws + 3525120);  // [4.8M halves]

    dim3 b256(256);
    const int gN = NBLK;                        // 196
    const int gE = (NE + 255) / 256;            // 3125
    const int gGem = (NN + 63) / 64;            // 782
    const int gPack = (73728 + 255) / 256;      // 288

    // ---- CSR build + dinv + weight pack ----
    zero_int_kernel<<<gN, b256, 0, stream>>>(deg, NN);
    hist_kernel<<<gE, b256, 0, stream>>>(dst, deg);
    scan1_kernel<<<gN, b256, 0, stream>>>(deg, excl, partials);
    scan3_kernel<<<gN, b256, 0, stream>>>(excl, partials, deg, rowstart, dinv, cursor);
    scatter_kernel<<<gE, b256, 0, stream>>>(src, dst, rowstart, cursor, csr_src);
    pack_all<<<gPack, b256, 0, stream>>>(W0, W1, W2, fcW, w0hi, w0lo, w1hi, w1lo,
                                         w2hi, w2lo, fchi, fclo);

    // ---- layer 0 GEMM: hs0 = (x@W0)*dinv ----
    mfma_gemm_f<KIN><<<gGem, dim3(512), 0, stream>>>(x, w0hi, w0lo, dinv, hsA, NN);

    // ---- fused: h1 = relu(gather(hs0)+b0); hs1 = (h1@W1)*dinv ----
    fused_gg<HIDD, false><<<gGem, dim3(512), 0, stream>>>(
        rowstart, dinv, csr_src, (const h4*)hsA, b0, w1hi, w1lo, nullptr, hsB, nullptr, NN);

    // ---- fused: h2 = relu(gather(hs1)+b1); hs2 = (h2@W2)*dinv ----
    fused_gg<HIDD, false><<<gGem, dim3(512), 0, stream>>>(
        rowstart, dinv, csr_src, (const h4*)hsB, b1, w2hi, w2lo, nullptr, hsA, nullptr, NN);

    // ---- fused: h3 = relu(gather(hs2)+b2); out = h3@fcW + fcb ----
    fused_gg<ODIM, true><<<gGem, dim3(512), 0, stream>>>(
        rowstart, dinv, csr_src, (const h4*)hsA, b2, fchi, fclo, fcb, nullptr, out, NN);
}

// Round 9
// 374.685 us; speedup vs baseline: 1.3010x; 1.3010x over previous
//
#include <hip/hip_runtime.h>

// GCN r9: revert r8's edge-balanced gather (serial chain, regressed). Per-node
// gather with 12 lanes/node x 8 feats: ONE dwordx4 load per edge per lane,
// 4-deep unroll. 768-thr blocks; GEMM phase = 4 row-groups x 3 col-groups.

constexpr int NN   = 50000;
constexpr int NE   = 800000;
constexpr int KIN  = 512;
constexpr int HIDD = 96;
constexpr int ODIM = 64;
constexpr int NBLK = (NN + 255) / 256;   // 196 scan blocks

typedef short bf16x8 __attribute__((ext_vector_type(8)));
typedef short s8v    __attribute__((ext_vector_type(8)));
typedef float f32x4  __attribute__((ext_vector_type(4)));
typedef _Float16 h8  __attribute__((ext_vector_type(8)));

__device__ inline short f2bf(float f) {               // RTN-even fp32 -> bf16 bits
    union { float f; unsigned u; } v; v.f = f;
    unsigned r = v.u + 0x7FFFu + ((v.u >> 16) & 1u);
    return (short)(r >> 16);
}
__device__ inline short f2bf_trunc(float f) {         // truncate (for lo residual)
    union { float f; unsigned u; } v; v.f = f;
    return (short)(v.u >> 16);
}
__device__ inline float bf2f(short h) {
    union { unsigned u; float f; } v; v.u = ((unsigned)(unsigned short)h) << 16;
    return v.f;
}

// ---------------- CSR build ----------------
__global__ void zero_int_kernel(int* __restrict__ p, int n) {
    int i = blockIdx.x * blockDim.x + threadIdx.x;
    if (i < n) p[i] = 0;
}

__global__ void hist_kernel(const int* __restrict__ dst, int* __restrict__ deg) {
    int e = blockIdx.x * blockDim.x + threadIdx.x;
    if (e < NE) atomicAdd(&deg[dst[e]], 1);
}

__global__ void scan1_kernel(const int* __restrict__ deg, int* __restrict__ excl,
                             int* __restrict__ partials) {
    __shared__ int tmp[256];
    const int tid = threadIdx.x;
    const int i = blockIdx.x * 256 + tid;
    const int v = (i < NN) ? deg[i] : 0;
    tmp[tid] = v;
    __syncthreads();
#pragma unroll
    for (int off = 1; off < 256; off <<= 1) {
        int t = (tid >= off) ? tmp[tid - off] : 0;
        __syncthreads();
        tmp[tid] += t;
        __syncthreads();
    }
    if (i < NN) excl[i] = tmp[tid] - v;
    if (tid == 255) partials[blockIdx.x] = tmp[tid];
}

__global__ void scan3_kernel(const int* __restrict__ excl, const int* __restrict__ partials,
                             const int* __restrict__ deg, int* __restrict__ rowstart,
                             float* __restrict__ dinv, int* __restrict__ cursor) {
    __shared__ int tmp[256];
    const int tid = threadIdx.x;
    tmp[tid] = (tid < (int)blockIdx.x) ? partials[tid] : 0;   // NBLK=196 <= 256
    __syncthreads();
#pragma unroll
    for (int off = 128; off > 0; off >>= 1) {
        if (tid < off) tmp[tid] += tmp[tid + off];
        __syncthreads();
    }
    const int boff = tmp[0];
    const int i = blockIdx.x * 256 + tid;
    if (i < NN) {
        rowstart[i] = excl[i] + boff;
        dinv[i] = 1.0f / sqrtf((float)deg[i] + 1.0f);
        cursor[i] = 0;
    }
    if (blockIdx.x == 0 && tid == 0) rowstart[NN] = NE;   // sentinel
}

__global__ void scatter_kernel(const int* __restrict__ src, const int* __restrict__ dst,
                               const int* __restrict__ rowstart, int* __restrict__ cursor,
                               int* __restrict__ csr_src) {
    int e = blockIdx.x * blockDim.x + threadIdx.x;
    if (e < NE) {
        const int d = dst[e];
        const int pos = rowstart[d] + atomicAdd(&cursor[d], 1);
        csr_src[pos] = src[e];
    }
}

// ---------------- fused W hi/lo pack (MFMA B-frag order) ----------------
__global__ void pack_all(const float* __restrict__ W0, const float* __restrict__ W1,
                         const float* __restrict__ W2, const float* __restrict__ FC,
                         short* __restrict__ w0hi, short* __restrict__ w0lo,
                         short* __restrict__ w1hi, short* __restrict__ w1lo,
                         short* __restrict__ w2hi, short* __restrict__ w2lo,
                         short* __restrict__ fchi, short* __restrict__ fclo) {
    const int idx = blockIdx.x * 256 + threadIdx.x;
    const float* W; short *hi, *lo; int M, li;
    if      (idx < 49152) { W = W0; hi = w0hi; lo = w0lo; M = 96; li = idx; }
    else if (idx < 58368) { W = W1; hi = w1hi; lo = w1lo; M = 96; li = idx - 49152; }
    else if (idx < 67584) { W = W2; hi = w2hi; lo = w2lo; M = 96; li = idx - 58368; }
    else if (idx < 73728) { W = FC; hi = fchi; lo = fclo; M = 64; li = idx - 67584; }
    else return;
    const int CT = M >> 4;
    const int j = li & 7;
    const int lane = (li >> 3) & 63;
    const int t = li >> 9;             // kc*CT + ct
    const int ct = t % CT;
    const int kc = t / CT;
    const int k = kc * 32 + (lane >> 4) * 8 + j;
    const int n = ct * 16 + (lane & 15);
    const float w = W[k * M + n];
    const short h = f2bf(w);
    hi[li] = h;
    lo[li] = f2bf_trunc(w - bf2f(h));
}

// ---------------- layer-0 GEMM: fp32 A, split-bf16, split-K x2, LDS-staged W ----
template <int K>   // 512
__launch_bounds__(512, 6)
__global__ void mfma_gemm_f(const float* __restrict__ A, const short* __restrict__ Whi,
                            const short* __restrict__ Wlo, const float* __restrict__ dinv,
                            _Float16* __restrict__ C, int N) {
    constexpr int CT = 6;
    constexpr int KCH = K / 64;        // kc per half = 8
    constexpr int PH  = KCH / 2;       // 4 phases, 2 kc per half per phase
    __shared__ short sHi[4 * 3072];    // 24 KB
    __shared__ short sLo[4 * 3072];    // 24 KB

    const int tid = threadIdx.x;
    const int lane = tid & 63;
    const int wave = tid >> 6;
    const int rw = wave & 3;
    const int kh = wave >> 2;
    const int q = lane >> 4;
    const int m = lane & 15;
    const int row = blockIdx.x * 64 + rw * 16 + m;
    const int arow = (row < N) ? row : (N - 1);

    f32x4 acc[CT];
#pragma unroll
    for (int c = 0; c < CT; ++c) acc[c] = f32x4{0.f, 0.f, 0.f, 0.f};

    const float* ap = A + (size_t)arow * K + kh * (K / 2) + q * 8;
    float4 a0 = *(const float4*)(ap);
    float4 a1 = *(const float4*)(ap + 4);

#pragma unroll
    for (int p = 0; p < PH; ++p) {
#pragma unroll
        for (int i = 0; i < 3; ++i) {
            const int ci = i * 512 + tid;            // 0..1535
            const int slot = ci / 384;               // 384 f4 per group
            const int within = ci - slot * 384;
            const int kcg = (slot >> 1) * KCH + p * 2 + (slot & 1);
            const int so = kcg * 3072 + within * 8;
            const int doff = ci * 8;
            *(float4*)(sHi + doff) = *(const float4*)(Whi + so);
            *(float4*)(sLo + doff) = *(const float4*)(Wlo + so);
        }
        __syncthreads();

#pragma unroll
        for (int kc = 0; kc < 2; ++kc) {
            const float af[8] = {a0.x, a0.y, a0.z, a0.w, a1.x, a1.y, a1.z, a1.w};
            bf16x8 ahi, alo;
#pragma unroll
            for (int j = 0; j < 8; ++j) {
                const short h = f2bf(af[j]);
                ahi[j] = h;
                alo[j] = f2bf_trunc(af[j] - bf2f(h));
            }
            if (p * 2 + kc + 1 < KCH) {
                ap += 32;
                a0 = *(const float4*)(ap);
                a1 = *(const float4*)(ap + 4);
            }
            const int slot = kh * 2 + kc;
            const short* hbase = sHi + slot * 3072 + lane * 8;
            const short* lbase = sLo + slot * 3072 + lane * 8;
#pragma unroll
            for (int c = 0; c < CT; ++c) {
                const bf16x8 wh = *(const bf16x8*)(hbase + c * 512);
                const bf16x8 wl = *(const bf16x8*)(lbase + c * 512);
                acc[c] = __builtin_amdgcn_mfma_f32_16x16x32_bf16(ahi, wh, acc[c], 0, 0, 0);
                acc[c] = __builtin_amdgcn_mfma_f32_16x16x32_bf16(alo, wh, acc[c], 0, 0, 0);
                acc[c] = __builtin_amdgcn_mfma_f32_16x16x32_bf16(ahi, wl, acc[c], 0, 0, 0);
            }
        }
        __syncthreads();
    }

    // split-K combine via LDS (reuse staging buffers)
    float* sAcc = (float*)sHi;
    if (kh == 1) {
#pragma unroll
        for (int c = 0; c < CT; ++c)
            *(f32x4*)(sAcc + ((rw * 64 + lane) * CT + c) * 4) = acc[c];
    }
    __syncthreads();
    if (kh == 0) {
#pragma unroll
        for (int c = 0; c < CT; ++c) {
            const f32x4 o = *(const f32x4*)(sAcc + ((rw * 64 + lane) * CT + c) * 4);
            acc[c][0] += o[0]; acc[c][1] += o[1]; acc[c][2] += o[2]; acc[c][3] += o[3];
        }
        const int rbase = blockIdx.x * 64 + rw * 16 + q * 4;
#pragma unroll
        for (int r = 0; r < 4; ++r) {
            const int orow = rbase + r;
            if (orow < N) {
                const float s = dinv[orow];
#pragma unroll
                for (int c = 0; c < CT; ++c)
                    C[(size_t)orow * 96 + c * 16 + m] = (_Float16)(acc[c][r] * s);
            }
        }
    }
}

// ---------------- fused gather + GEMM (per-node, 16B loads) ----------------
// Gather: 768 thr = 64 nodes x 12 lanes; lane owns 8 feats = ONE dwordx4/edge.
// GEMM: 12 waves = 4 row-groups x 3 col-groups (col-group 2 idle when M=64).
constexpr int APAD = 104;   // LDS row stride in shorts (208 B = 13*16 B)
template <int M, bool FC>
__launch_bounds__(768, 6)
__global__ void fused_gg(const int* __restrict__ rowstart, const float* __restrict__ dinv,
                         const int* __restrict__ csr_src, const _Float16* __restrict__ hs,
                         const float* __restrict__ gb,
                         const short* __restrict__ Whi, const short* __restrict__ Wlo,
                         const float* __restrict__ bias2,
                         _Float16* __restrict__ Ch, float* __restrict__ Cf, int N) {
    constexpr int CT = M / 16;     // 6 or 4
    __shared__ short sAhi[64 * APAD];
    __shared__ short sAlo[64 * APAD];

    const int tid = threadIdx.x;
    const int nb = blockIdx.x * 64;
    const int nl = tid / 12;            // node in tile 0..63
    const int fl = tid - nl * 12;       // feat lane 0..11, owns feats [fl*8, fl*8+8)
    const int node = nb + nl;

    s8v hi8, lo8;
    if (node < N) {
        const _Float16* __restrict__ hp = hs + fl * 8;
        float acc0[8], acc1[8];
        {
            const h8 sv = *(const h8*)(hp + (size_t)node * 96);   // self-loop
#pragma unroll
            for (int e = 0; e < 8; ++e) { acc0[e] = (float)sv[e]; acc1[e] = 0.f; }
        }
        int j = rowstart[node];
        const int jend = rowstart[node + 1];
        for (; j + 4 <= jend; j += 4) {
            const int s0 = csr_src[j], s1 = csr_src[j + 1];
            const int s2 = csr_src[j + 2], s3 = csr_src[j + 3];
            const h8 v0 = *(const h8*)(hp + (size_t)s0 * 96);
            const h8 v1 = *(const h8*)(hp + (size_t)s1 * 96);
            const h8 v2 = *(const h8*)(hp + (size_t)s2 * 96);
            const h8 v3 = *(const h8*)(hp + (size_t)s3 * 96);
#pragma unroll
            for (int e = 0; e < 8; ++e) {
                acc0[e] += (float)v0[e] + (float)v2[e];
                acc1[e] += (float)v1[e] + (float)v3[e];
            }
        }
        for (; j < jend; ++j) {
            const h8 v0 = *(const h8*)(hp + (size_t)csr_src[j] * 96);
#pragma unroll
            for (int e = 0; e < 8; ++e) acc0[e] += (float)v0[e];
        }
        const float di = dinv[node];
#pragma unroll
        for (int e = 0; e < 8; ++e) {
            const float o = fmaxf(fmaf(di, acc0[e] + acc1[e], gb[fl * 8 + e]), 0.0f);
            const short h = f2bf(o);
            hi8[e] = h;
            lo8[e] = f2bf_trunc(o - bf2f(h));
        }
    } else {
#pragma unroll
        for (int e = 0; e < 8; ++e) { hi8[e] = 0; lo8[e] = 0; }
    }
    *(s8v*)(sAhi + nl * APAD + fl * 8) = hi8;
    *(s8v*)(sAlo + nl * APAD + fl * 8) = lo8;
    __syncthreads();

    // ---- GEMM phase: 12 waves = 4 row groups x 3 col groups (2 tiles each) ----
    const int lane = tid & 63;
    const int wave = tid >> 6;
    const int rw = wave & 3;
    const int c0 = (wave >> 2) * 2;     // 0,2,4
    const int q = lane >> 4;
    const int m = lane & 15;

    if (c0 < CT) {
        bf16x8 Ah[3], Al[3];
#pragma unroll
        for (int kc = 0; kc < 3; ++kc) {
            const int off = (rw * 16 + m) * APAD + kc * 32 + q * 8;
            Ah[kc] = *(const bf16x8*)(sAhi + off);
            Al[kc] = *(const bf16x8*)(sAlo + off);
        }

        f32x4 gacc[2];
        gacc[0] = f32x4{0.f, 0.f, 0.f, 0.f};
        gacc[1] = f32x4{0.f, 0.f, 0.f, 0.f};

#pragma unroll
        for (int kc = 0; kc < 3; ++kc) {
#pragma unroll
            for (int c = 0; c < 2; ++c) {
                const int fo = ((kc * CT + c0 + c) * 64 + lane) * 8;
                const bf16x8 wh = *(const bf16x8*)(Whi + fo);
                const bf16x8 wl = *(const bf16x8*)(Wlo + fo);
                gacc[c] = __builtin_amdgcn_mfma_f32_16x16x32_bf16(Ah[kc], wh, gacc[c], 0, 0, 0);
                gacc[c] = __builtin_amdgcn_mfma_f32_16x16x32_bf16(Al[kc], wh, gacc[c], 0, 0, 0);
                gacc[c] = __builtin_amdgcn_mfma_f32_16x16x32_bf16(Ah[kc], wl, gacc[c], 0, 0, 0);
            }
        }

        const int rbase = nb + rw * 16 + q * 4;
#pragma unroll
        for (int r = 0; r < 4; ++r) {
            const int orow = rbase + r;
            if (orow < N) {
                if (FC) {
#pragma unroll
                    for (int c = 0; c < 2; ++c)
                        Cf[(size_t)orow * M + (c0 + c) * 16 + m] = gacc[c][r] + bias2[(c0 + c) * 16 + m];
                } else {
                    const float s = dinv[orow];
#pragma unroll
                    for (int c = 0; c < 2; ++c)
                        Ch[(size_t)orow * M + (c0 + c) * 16 + m] = (_Float16)(gacc[c][r] * s);
                }
            }
        }
    }
}

extern "C" void kernel_launch(void* const* d_in, const int* in_sizes, int n_in,
                              void* d_out, int out_size, void* d_ws, size_t ws_size,
                              hipStream_t stream) {
    const float* x   = (const float*)d_in[0];
    const int*   ei  = (const int*)d_in[1];
    const float* W0  = (const float*)d_in[2];
    const float* b0  = (const float*)d_in[3];
    const float* W1  = (const float*)d_in[4];
    const float* b1  = (const float*)d_in[5];
    const float* W2  = (const float*)d_in[6];
    const float* b2  = (const float*)d_in[7];
    const float* fcW = (const float*)d_in[8];
    const float* fcb = (const float*)d_in[9];
    float* out = (float*)d_out;

    const int* src = ei;
    const int* dst = ei + NE;

    float* ws = (float*)d_ws;
    float* dinv     = ws;                       // [50000]
    int*   deg      = (int*)(ws + 50176);
    int*   excl     = (int*)(ws + 100352);
    int*   cursor   = (int*)(ws + 150528);
    int*   rowstart = (int*)(ws + 200704);      // [50001] (sentinel)
    int*   partials = (int*)(ws + 250880);      // [256]
    int*   csr_src  = (int*)(ws + 251136);      // [800000]
    short* w0hi = (short*)(ws + 1051392);       // [49152] shorts
    short* w0lo = (short*)(ws + 1075968);
    short* w1hi = (short*)(ws + 1100544);       // [9216] shorts
    short* w1lo = (short*)(ws + 1105152);
    short* w2hi = (short*)(ws + 1109760);
    short* w2lo = (short*)(ws + 1114368);
    short* fchi = (short*)(ws + 1118976);       // [6144] shorts
    short* fclo = (short*)(ws + 1122048);
    _Float16* hsA = (_Float16*)(ws + 1125120);  // [4.8M halves]
    _Float16* hsB = (_Float16*)(ws + 3525120);  // [4.8M halves]

    dim3 b256(256);
    const int gN = NBLK;                        // 196
    const int gE = (NE + 255) / 256;            // 3125
    const int gGem = (NN + 63) / 64;            // 782
    const int gPack = (73728 + 255) / 256;      // 288

    // ---- CSR build + dinv + weight pack ----
    zero_int_kernel<<<gN, b256, 0, stream>>>(deg, NN);
    hist_kernel<<<gE, b256, 0, stream>>>(dst, deg);
    scan1_kernel<<<gN, b256, 0, stream>>>(deg, excl, partials);
    scan3_kernel<<<gN, b256, 0, stream>>>(excl, partials, deg, rowstart, dinv, cursor);
    scatter_kernel<<<gE, b256, 0, stream>>>(src, dst, rowstart, cursor, csr_src);
    pack_all<<<gPack, b256, 0, stream>>>(W0, W1, W2, fcW, w0hi, w0lo, w1hi, w1lo,
                                         w2hi, w2lo, fchi, fclo);

    // ---- layer 0 GEMM: hs0 = (x@W0)*dinv ----
    mfma_gemm_f<KIN><<<gGem, dim3(512), 0, stream>>>(x, w0hi, w0lo, dinv, hsA, NN);

    // ---- fused: h1 = relu(gather(hs0)+b0); hs1 = (h1@W1)*dinv ----
    fused_gg<HIDD, false><<<gGem, dim3(768), 0, stream>>>(
        rowstart, dinv, csr_src, hsA, b0, w1hi, w1lo, nullptr, hsB, nullptr, NN);

    // ---- fused: h2 = relu(gather(hs1)+b1); hs2 = (h2@W2)*dinv ----
    fused_gg<HIDD, false><<<gGem, dim3(768), 0, stream>>>(
        rowstart, dinv, csr_src, hsB, b1, w2hi, w2lo, nullptr, hsA, nullptr, NN);

    // ---- fused: h3 = relu(gather(hs2)+b2); out = h3@fcW + fcb ----
    fused_gg<ODIM, true><<<gGem, dim3(768), 0, stream>>>(
        rowstart, dinv, csr_src, hsA, b2, fchi, fclo, fcb, nullptr, out, NN);
}